// Round 7
// baseline (771.965 us; speedup 1.0000x reference)
//
#include <hip/hip_runtime.h>
#include <hip/hip_bf16.h>

typedef __bf16 bf16;
typedef __bf16 bf16x4 __attribute__((ext_vector_type(4)));
typedef __bf16 bf16x8 __attribute__((ext_vector_type(8)));
typedef float f32x4 __attribute__((ext_vector_type(4)));

#define NB   32768
#define EMB  768
#define MSUB 32
#define KC   256
#define DSUB 24

// ws layout (bytes):
//   [0,     384K )  cb_tb : bf16 [32][24][256]  (d-major, k contiguous)
//   [1M,  2.125M)  rot_bf: bf16 [768][768]
//   [4M,   100M )  xr    : fp32 [32768][768]    (natural layout)

__device__ __forceinline__ bf16x8 cvt8(float4 a, float4 b) {
    bf16x8 r;
    r[0] = (bf16)a.x; r[1] = (bf16)a.y; r[2] = (bf16)a.z; r[3] = (bf16)a.w;
    r[4] = (bf16)b.x; r[5] = (bf16)b.y; r[6] = (bf16)b.z; r[7] = (bf16)b.w;
    return r;
}

// ---------------------------------------------------------------- kernel 0
__global__ __launch_bounds__(256, 4)
void pq_prep(const float* __restrict__ cb, const float* __restrict__ rot,
             bf16* __restrict__ cb_tb, bf16* __restrict__ rot_bf) {
    const int b = blockIdx.x;
    const int t = threadIdx.x;
    if (b < 288) {                       // rot: 768*768 = 288*2048
        const int o = b * 2048 + t * 8;
        float4 a0 = *(const float4*)(rot + o);
        float4 a1 = *(const float4*)(rot + o + 4);
        *(bf16x8*)(rot_bf + o) = cvt8(a0, a1);
    } else {                             // cb transpose+cvt: [m][k][d] -> bf16 [m][d][k]
        const int m = b - 288;           // 0..31, t = k
        const float* src = cb + (size_t)(m * KC + t) * DSUB;
        float v[24];
        #pragma unroll
        for (int i = 0; i < 6; ++i)
            *(float4*)(v + 4 * i) = *(const float4*)(src + 4 * i);
        #pragma unroll
        for (int d = 0; d < DSUB; ++d)
            cb_tb[((size_t)m * DSUB + d) * KC + t] = (bf16)v[d];
    }
}

// ---------------------------------------------------------------- kernel 1
// xr = x @ rot^T via swapped MFMA: D[j][row] = mfma(A=rot_frag, B=x_frag).
// Acc regs hold 4 CONSECUTIVE j per lane -> direct f32x4 stores.
__global__ __launch_bounds__(512, 3)
void pq_rot(const float* __restrict__ x, const bf16* __restrict__ rot_bf,
            float* __restrict__ xr) {
    __shared__ bf16 g_lds[96 * 32 * 8];   // x bf16 granules [e8][row][slot], 48 KiB

    const int tid  = threadIdx.x;
    const int w    = tid >> 6;
    const int lane = tid & 63;
    const int l15  = lane & 15;
    const int lg   = lane >> 4;
    const int rowbase = blockIdx.x * 32;

    #pragma unroll
    for (int i = 0; i < 6; ++i) {
        const int oct = i * 512 + tid;
        const int row = oct & 31;
        const int e8  = oct >> 5;
        const float* xp = x + (size_t)(rowbase + row) * EMB + e8 * 8;
        *(bf16x8*)&g_lds[(e8 * 32 + row) * 8] =
            cvt8(*(const float4*)xp, *(const float4*)(xp + 4));
    }
    __syncthreads();

    f32x4 acc[2][6];
    #pragma unroll
    for (int rt = 0; rt < 2; ++rt)
        #pragma unroll
        for (int jt = 0; jt < 6; ++jt)
            acc[rt][jt] = (f32x4){0.f, 0.f, 0.f, 0.f};

    const int jbase = w * 96;
    #pragma unroll 2
    for (int e0 = 0; e0 < EMB; e0 += 32) {
        bf16x8 xfrag[2];
        #pragma unroll
        for (int rt = 0; rt < 2; ++rt)
            xfrag[rt] = *(const bf16x8*)&g_lds[(((e0 >> 3) + lg) * 32 + rt * 16 + l15) * 8];
        #pragma unroll
        for (int jt = 0; jt < 6; ++jt) {
            const bf16* bp = rot_bf + (size_t)(jbase + jt * 16 + l15) * EMB + e0 + lg * 8;
            bf16x8 rotfrag = *(const bf16x8*)bp;
            acc[0][jt] = __builtin_amdgcn_mfma_f32_16x16x32_bf16(rotfrag, xfrag[0], acc[0][jt], 0, 0, 0);
            acc[1][jt] = __builtin_amdgcn_mfma_f32_16x16x32_bf16(rotfrag, xfrag[1], acc[1][jt], 0, 0, 0);
        }
    }

    #pragma unroll
    for (int rt = 0; rt < 2; ++rt) {
        #pragma unroll
        for (int jt = 0; jt < 6; ++jt) {
            float* p = xr + (size_t)(rowbase + rt * 16 + l15) * EMB
                          + jbase + jt * 16 + lg * 4;
            *(f32x4*)p = acc[rt][jt];
        }
    }
}

// ---------------------------------------------------------------- kernel 2
// scores with LDS slab re-ordered stores. Block = 4 rows x 16 m (one m-half).
// Compute: wave w owns m = mbase + mm*8 + w; k = 4*lane in-lane (f32x4).
// Stage into stg[mm][row][mloc][k] (32 KB slab), then drain as DENSE spans:
// wave w drains (row = w>>1, 4 consecutive m = (w&1)*4..) -> 4 KB contiguous
// ascending per wave, 32 KB contiguous per block-slab. Slab 0 stores overlap
// slab 1 compute. 2 barriers/block, 64 KB LDS -> 2 blocks/CU.
__global__ __launch_bounds__(512, 2)
void pq_scores3(const float* __restrict__ xr, const bf16* __restrict__ cb_tb,
                float* __restrict__ out) {
    __shared__ float stg[2][4][8][256];   // 64 KiB

    const int tid  = threadIdx.x;
    const int lane = tid & 63;
    const int w    = tid >> 6;

    // bijective XCD swizzle: 16384 blocks, 2048 contiguous per XCD
    const int bid = (int)blockIdx.x;
    const int swz = (bid & 7) * 2048 + (bid >> 3);
    const int q   = swz >> 1;            // row-quad 0..8191
    const int mh  = swz & 1;             // m-half
    const int rowbase = q * 4;
    const int mbase   = mh * 16;

    #pragma unroll 1
    for (int mm = 0; mm < 2; ++mm) {
        const int m = mbase + mm * 8 + w;

        // cbv[d][kk] = cb[m][d][4*lane+kk], bf16 -> f32 (96 VGPR)
        f32x4 cbv[DSUB];
        const bf16* cbp = cb_tb + (size_t)m * (DSUB * KC) + 4 * lane;
        #pragma unroll
        for (int d = 0; d < DSUB; ++d) {
            bf16x4 c4 = *(const bf16x4*)(cbp + d * KC);
            cbv[d] = (f32x4){(float)c4[0], (float)c4[1], (float)c4[2], (float)c4[3]};
        }

        // compute 4 rows into slab mm (xs loads are wave-uniform -> s_load)
        #pragma unroll
        for (int r = 0; r < 4; ++r) {
            const float* xp = xr + (size_t)(rowbase + r) * EMB + m * DSUB;
            float xs[DSUB];
            #pragma unroll
            for (int d = 0; d < DSUB; ++d) xs[d] = xp[d];
            f32x4 acc = (f32x4){0.f, 0.f, 0.f, 0.f};
            #pragma unroll
            for (int d = 0; d < DSUB; ++d) acc += cbv[d] * xs[d];
            *(f32x4*)&stg[mm][r][w][4 * lane] = acc;
        }

        __syncthreads();   // slab mm complete

        // drain slab mm: dense contiguous spans
        const int dr = w >> 1;            // row 0..3
        const int dh = w & 1;             // which 4-m half of the 8-m slab
        const float* sp = &stg[mm][dr][dh * 4][0];
        float* op = out + ((size_t)(rowbase + dr) * MSUB + mbase + mm * 8 + dh * 4) * KC
                        + 4 * lane;
        #pragma unroll
        for (int i = 0; i < 4; ++i) {
            f32x4 v = *(const f32x4*)(sp + i * 256 + 4 * lane);
            *(f32x4*)(op + i * KC) = v;   // 1 KiB/instr, 4 KiB ascending/wave
        }
        // no barrier needed: next mm writes the OTHER slab
    }
}

extern "C" void kernel_launch(void* const* d_in, const int* in_sizes, int n_in,
                              void* d_out, int out_size, void* d_ws, size_t ws_size,
                              hipStream_t stream) {
    const float* x   = (const float*)d_in[0];   // [32768, 768]
    const float* cbk = (const float*)d_in[1];   // [32, 256, 24]
    const float* rot = (const float*)d_in[2];   // [768, 768]
    float* out = (float*)d_out;                 // [32768, 32, 256]

    char* ws = (char*)d_ws;
    bf16*  cb_tb  = (bf16*)(ws);
    bf16*  rot_bf = (bf16*)(ws + (1u << 20));
    float* xr     = (float*)(ws + (4u << 20));

    hipLaunchKernelGGL(pq_prep,    dim3(320),   dim3(256), 0, stream, cbk, rot, cb_tb, rot_bf);
    hipLaunchKernelGGL(pq_rot,     dim3(1024),  dim3(512), 0, stream, x, rot_bf, xr);
    hipLaunchKernelGGL(pq_scores3, dim3(16384), dim3(512), 0, stream, xr, cb_tb, out);
}

// Round 8
// 463.464 us; speedup vs baseline: 1.6656x; 1.6656x over previous
//
#include <hip/hip_runtime.h>
#include <hip/hip_bf16.h>

typedef __bf16 bf16;
typedef __bf16 bf16x4 __attribute__((ext_vector_type(4)));
typedef __bf16 bf16x8 __attribute__((ext_vector_type(8)));
typedef float f32x4 __attribute__((ext_vector_type(4)));

#define NB   32768
#define EMB  768
#define MSUB 32
#define KC   256
#define DSUB 24

// ws layout (bytes):
//   [0,     768K )  cb_t  : fp32 [32][24][256]  (d-major, k contiguous)
//   [1M,  2.125M)  rot_bf: bf16 [768][768]
//   [4M,    52M )  xrb   : bf16 [32768][768]    (natural layout)

__device__ __forceinline__ bf16x8 cvt8(float4 a, float4 b) {
    bf16x8 r;
    r[0] = (bf16)a.x; r[1] = (bf16)a.y; r[2] = (bf16)a.z; r[3] = (bf16)a.w;
    r[4] = (bf16)b.x; r[5] = (bf16)b.y; r[6] = (bf16)b.z; r[7] = (bf16)b.w;
    return r;
}

// ---------------------------------------------------------------- kernel 0
__global__ __launch_bounds__(256, 4)
void pq_prep(const float* __restrict__ cb, const float* __restrict__ rot,
             float* __restrict__ cb_t, bf16* __restrict__ rot_bf) {
    const int b = blockIdx.x;
    const int t = threadIdx.x;
    if (b < 288) {                       // rot: 768*768 = 288*2048
        const int o = b * 2048 + t * 8;
        float4 a0 = *(const float4*)(rot + o);
        float4 a1 = *(const float4*)(rot + o + 4);
        *(bf16x8*)(rot_bf + o) = cvt8(a0, a1);
    } else {                             // cb transpose: [m][k][d] -> fp32 [m][d][k]
        const int m = b - 288;           // 0..31, t = k
        const float* src = cb + (size_t)(m * KC + t) * DSUB;
        float v[24];
        #pragma unroll
        for (int i = 0; i < 6; ++i)
            *(float4*)(v + 4 * i) = *(const float4*)(src + 4 * i);
        #pragma unroll
        for (int d = 0; d < DSUB; ++d)
            cb_t[((size_t)m * DSUB + d) * KC + t] = v[d];
    }
}

// ---------------------------------------------------------------- kernel 1
// xr = x @ rot^T via swapped MFMA: D[j][row] = mfma(A=rot_frag, B=x_frag).
// Acc regs hold 4 CONSECUTIVE j per lane -> direct bf16x4 stores.
__global__ __launch_bounds__(512, 3)
void pq_rot(const float* __restrict__ x, const bf16* __restrict__ rot_bf,
            bf16* __restrict__ xrb) {
    __shared__ bf16 g_lds[96 * 32 * 8];   // x bf16 granules [e8][row][slot], 48 KiB

    const int tid  = threadIdx.x;
    const int w    = tid >> 6;
    const int lane = tid & 63;
    const int l15  = lane & 15;
    const int lg   = lane >> 4;
    const int rowbase = blockIdx.x * 32;

    #pragma unroll
    for (int i = 0; i < 6; ++i) {
        const int oct = i * 512 + tid;
        const int row = oct & 31;
        const int e8  = oct >> 5;
        const float* xp = x + (size_t)(rowbase + row) * EMB + e8 * 8;
        *(bf16x8*)&g_lds[(e8 * 32 + row) * 8] =
            cvt8(*(const float4*)xp, *(const float4*)(xp + 4));
    }
    __syncthreads();

    f32x4 acc[2][6];
    #pragma unroll
    for (int rt = 0; rt < 2; ++rt)
        #pragma unroll
        for (int jt = 0; jt < 6; ++jt)
            acc[rt][jt] = (f32x4){0.f, 0.f, 0.f, 0.f};

    const int jbase = w * 96;
    #pragma unroll 2
    for (int e0 = 0; e0 < EMB; e0 += 32) {
        bf16x8 xfrag[2];
        #pragma unroll
        for (int rt = 0; rt < 2; ++rt)
            xfrag[rt] = *(const bf16x8*)&g_lds[(((e0 >> 3) + lg) * 32 + rt * 16 + l15) * 8];
        #pragma unroll
        for (int jt = 0; jt < 6; ++jt) {
            const bf16* bp = rot_bf + (size_t)(jbase + jt * 16 + l15) * EMB + e0 + lg * 8;
            bf16x8 rotfrag = *(const bf16x8*)bp;
            acc[0][jt] = __builtin_amdgcn_mfma_f32_16x16x32_bf16(rotfrag, xfrag[0], acc[0][jt], 0, 0, 0);
            acc[1][jt] = __builtin_amdgcn_mfma_f32_16x16x32_bf16(rotfrag, xfrag[1], acc[1][jt], 0, 0, 0);
        }
    }

    // epilogue: acc[rt][jt] reg r = xr[rowbase+rt*16+l15][jbase+jt*16+lg*4+r]
    #pragma unroll
    for (int rt = 0; rt < 2; ++rt) {
        #pragma unroll
        for (int jt = 0; jt < 6; ++jt) {
            bf16x4 v;
            #pragma unroll
            for (int r = 0; r < 4; ++r) v[r] = (bf16)acc[rt][jt][r];
            bf16* p = xrb + (size_t)(rowbase + rt * 16 + l15) * EMB
                          + jbase + jt * 16 + lg * 4;
            *(bf16x4*)p = v;
        }
    }
}

// ---------------------------------------------------------------- kernel 2
// scores, pure VALU, grid-strided rows for a DENSE machine-wide write front:
// block b handles rows {b + r*2048}; at any instant ~768 resident blocks
// write ~768 CONSECUTIVE rows (m-islands mm*4+w) -> monotone advancing
// window, fillBuffer-shaped. Lane owns k=4*lane..+3: every store is one
// complete 1 KiB line. 256 thr, VGPR<=128 -> 4 blocks/CU target.
__global__ __launch_bounds__(256, 4)
void pq_scores5(const bf16* __restrict__ xrb, const float* __restrict__ cb_t,
                float* __restrict__ out) {
    const int tid  = threadIdx.x;
    const int lane = tid & 63;
    const int w    = tid >> 6;           // 0..3
    const int bid  = (int)blockIdx.x;    // 0..2047

    #pragma unroll 1
    for (int mm = 0; mm < 8; ++mm) {
        const int m = mm * 4 + w;

        // cbv[d][kk] = cb_t[m][d][4*lane+kk]  (96 VGPR, L2-resident source)
        f32x4 cbv[DSUB];
        const float* cbp = cb_t + (size_t)m * (DSUB * KC) + 4 * lane;
        #pragma unroll
        for (int d = 0; d < DSUB; ++d)
            cbv[d] = *(const f32x4*)(cbp + d * KC);

        #pragma unroll 1
        for (int r = 0; r < 16; ++r) {
            const int row = bid + r * 2048;
            const bf16* xp = xrb + (size_t)row * EMB + m * DSUB;
            bf16x8 x0 = *(const bf16x8*)(xp);
            bf16x8 x1 = *(const bf16x8*)(xp + 8);
            bf16x8 x2 = *(const bf16x8*)(xp + 16);

            f32x4 acc = (f32x4){0.f, 0.f, 0.f, 0.f};
            #pragma unroll
            for (int i = 0; i < 8; ++i) acc += cbv[i]      * (float)x0[i];
            #pragma unroll
            for (int i = 0; i < 8; ++i) acc += cbv[i + 8]  * (float)x1[i];
            #pragma unroll
            for (int i = 0; i < 8; ++i) acc += cbv[i + 16] * (float)x2[i];

            float* op = out + ((size_t)row * MSUB + m) * KC + 4 * lane;
            __builtin_nontemporal_store(acc, (f32x4*)op);
        }
    }
}

extern "C" void kernel_launch(void* const* d_in, const int* in_sizes, int n_in,
                              void* d_out, int out_size, void* d_ws, size_t ws_size,
                              hipStream_t stream) {
    const float* x   = (const float*)d_in[0];   // [32768, 768]
    const float* cbk = (const float*)d_in[1];   // [32, 256, 24]
    const float* rot = (const float*)d_in[2];   // [768, 768]
    float* out = (float*)d_out;                 // [32768, 32, 256]

    char* ws = (char*)d_ws;
    float* cb_t   = (float*)(ws);
    bf16*  rot_bf = (bf16*)(ws + (1u << 20));
    bf16*  xrb    = (bf16*)(ws + (4u << 20));

    hipLaunchKernelGGL(pq_prep,    dim3(320),  dim3(256), 0, stream, cbk, rot, cb_t, rot_bf);
    hipLaunchKernelGGL(pq_rot,     dim3(1024), dim3(512), 0, stream, x, rot_bf, xrb);
    hipLaunchKernelGGL(pq_scores5, dim3(2048), dim3(256), 0, stream, xrb, cb_t, out);
}

// Round 9
// 446.449 us; speedup vs baseline: 1.7291x; 1.0381x over previous
//
#include <hip/hip_runtime.h>
#include <hip/hip_bf16.h>

typedef __bf16 bf16;
typedef __bf16 bf16x4 __attribute__((ext_vector_type(4)));
typedef __bf16 bf16x8 __attribute__((ext_vector_type(8)));
typedef float f32x4 __attribute__((ext_vector_type(4)));

#define NB   32768
#define EMB  768
#define MSUB 32
#define KC   256
#define DSUB 24

// ws layout (bytes):
//   [0,     512K )  cb_pad: bf16 [32][256][32]  (d padded 24->32 with zeros)
//   [1M,  2.125M)  rot_bf: bf16 [768][768]
//   [4M,    54M )  xrb   : bf16 [32768][768]    (natural layout)

__device__ __forceinline__ bf16x8 cvt8(float4 a, float4 b) {
    bf16x8 r;
    r[0] = (bf16)a.x; r[1] = (bf16)a.y; r[2] = (bf16)a.z; r[3] = (bf16)a.w;
    r[4] = (bf16)b.x; r[5] = (bf16)b.y; r[6] = (bf16)b.z; r[7] = (bf16)b.w;
    return r;
}

// ---------------------------------------------------------------- kernel 0
__global__ __launch_bounds__(256, 4)
void pq_prep(const float* __restrict__ cb, const float* __restrict__ rot,
             bf16* __restrict__ cb_pad, bf16* __restrict__ rot_bf) {
    const int b = blockIdx.x;
    const int t = threadIdx.x;
    if (b < 288) {                       // rot: 768*768 = 288*2048
        const int o = b * 2048 + t * 8;
        float4 a0 = *(const float4*)(rot + o);
        float4 a1 = *(const float4*)(rot + o + 4);
        *(bf16x8*)(rot_bf + o) = cvt8(a0, a1);
    } else {                             // cb pad+cvt: [m][k][24] -> bf16 [m][k][32]
        const int o  = (b - 288) * 2048 + t * 8;   // 32*256*32 = 128*2048
        const int m  = o >> 13;
        const int k  = (o >> 5) & 255;
        const int d0 = o & 31;           // 0,8,16,24
        bf16x8 v;
        if (d0 < DSUB) {
            const float* cp = cb + (size_t)(m * KC + k) * DSUB + d0;
            v = cvt8(*(const float4*)cp, *(const float4*)(cp + 4));
        } else {
            const float4 fz = {0.f, 0.f, 0.f, 0.f};
            v = cvt8(fz, fz);
        }
        *(bf16x8*)(cb_pad + o) = v;
    }
}

// ---------------------------------------------------------------- kernel 1
// xr = x @ rot^T via swapped MFMA: D[j][row] = mfma(A=rot_frag, B=x_frag).
// Acc regs hold 4 CONSECUTIVE j per lane -> direct bf16x4 stores.
__global__ __launch_bounds__(512, 3)
void pq_rot(const float* __restrict__ x, const bf16* __restrict__ rot_bf,
            bf16* __restrict__ xrb) {
    __shared__ bf16 g_lds[96 * 32 * 8];   // x bf16 granules [e8][row][slot], 48 KiB

    const int tid  = threadIdx.x;
    const int w    = tid >> 6;
    const int lane = tid & 63;
    const int l15  = lane & 15;
    const int lg   = lane >> 4;
    const int rowbase = blockIdx.x * 32;

    #pragma unroll
    for (int i = 0; i < 6; ++i) {
        const int oct = i * 512 + tid;
        const int row = oct & 31;
        const int e8  = oct >> 5;
        const float* xp = x + (size_t)(rowbase + row) * EMB + e8 * 8;
        *(bf16x8*)&g_lds[(e8 * 32 + row) * 8] =
            cvt8(*(const float4*)xp, *(const float4*)(xp + 4));
    }
    __syncthreads();

    f32x4 acc[2][6];
    #pragma unroll
    for (int rt = 0; rt < 2; ++rt)
        #pragma unroll
        for (int jt = 0; jt < 6; ++jt)
            acc[rt][jt] = (f32x4){0.f, 0.f, 0.f, 0.f};

    const int jbase = w * 96;
    #pragma unroll 2
    for (int e0 = 0; e0 < EMB; e0 += 32) {
        bf16x8 xfrag[2];
        #pragma unroll
        for (int rt = 0; rt < 2; ++rt)
            xfrag[rt] = *(const bf16x8*)&g_lds[(((e0 >> 3) + lg) * 32 + rt * 16 + l15) * 8];
        #pragma unroll
        for (int jt = 0; jt < 6; ++jt) {
            const bf16* bp = rot_bf + (size_t)(jbase + jt * 16 + l15) * EMB + e0 + lg * 8;
            bf16x8 rotfrag = *(const bf16x8*)bp;
            acc[0][jt] = __builtin_amdgcn_mfma_f32_16x16x32_bf16(rotfrag, xfrag[0], acc[0][jt], 0, 0, 0);
            acc[1][jt] = __builtin_amdgcn_mfma_f32_16x16x32_bf16(rotfrag, xfrag[1], acc[1][jt], 0, 0, 0);
        }
    }

    #pragma unroll
    for (int rt = 0; rt < 2; ++rt) {
        #pragma unroll
        for (int jt = 0; jt < 6; ++jt) {
            bf16x4 v;
            #pragma unroll
            for (int r = 0; r < 4; ++r) v[r] = (bf16)acc[rt][jt][r];
            bf16* p = xrb + (size_t)(rowbase + rt * 16 + l15) * EMB
                          + jbase + jt * 16 + lg * 4;
            *(bf16x4*)p = v;
        }
    }
}

// ---------------------------------------------------------------- kernel 2
// scores via MFMA (removes the 328 us VALU floor of the scalar-FMA version).
// Block = 4 waves / 16 rows. Phase mm: wave w computes m = mm*4+w with
// swapped MFMA D[kc][docrow] = mfma(A=cb_frag, B=xs_frag): lane holds 4
// consecutive k for docrow=lane&15. Stage to padded LDS slab, barrier, then
// wave w drains rows w*4..w*4+3 as 4 KB CONTIGUOUS spans (4 consecutive m);
// block-phase burst = 64 KB. Plain stores (L2 aggregates).
__global__ __launch_bounds__(256, 2)
void pq_scores6(const bf16* __restrict__ xrb, const bf16* __restrict__ cb_pad,
                float* __restrict__ out) {
    __shared__ float stg[16][4][260];   // 66,560 B; pad 260 -> conflict-free min

    const int tid  = threadIdx.x;
    const int lane = tid & 63;
    const int w    = tid >> 6;          // 0..3
    const int l15  = lane & 15;
    const int hi   = lane >> 4;         // 0..3

    // XCD-bijective swizzle: 2048 blocks, 256 contiguous rowtiles per XCD
    const int bid = (int)blockIdx.x;
    const int swz = (bid & 7) * 256 + (bid >> 3);
    const int rowbase = swz * 16;

    #pragma unroll 1
    for (int mm = 0; mm < 8; ++mm) {
        const int m = mm * 4 + w;

        // xs B-frag: lane -> xrb[rowbase+l15][m*24 + hi*8 ..+7]
        // (hi==3 reads d=24..31: garbage, but multiplied by cb_pad zeros)
        const bf16* xp = xrb + (size_t)(rowbase + l15) * EMB + m * DSUB + hi * 8;
        bf16x8 xfrag = *(const bf16x8*)xp;

        // 16 k-tiles: A-frag = cb_pad[m][kt*16+l15][hi*8 ..+7]
        const bf16* cbm = cb_pad + (size_t)m * (KC * 32);
        f32x4 acc[16];
        #pragma unroll
        for (int kt = 0; kt < 16; ++kt) {
            bf16x8 cfrag = *(const bf16x8*)(cbm + (kt * 16 + l15) * 32 + hi * 8);
            acc[kt] = __builtin_amdgcn_mfma_f32_16x16x32_bf16(
                cfrag, xfrag, (f32x4){0.f, 0.f, 0.f, 0.f}, 0, 0, 0);
        }

        // stage: lane l, reg r -> D[kc = kt*16+hi*4+r][docrow = l15]
        #pragma unroll
        for (int kt = 0; kt < 16; ++kt)
            *(f32x4*)&stg[l15][w][kt * 16 + hi * 4] = acc[kt];

        __syncthreads();

        // drain: wave w -> rows w*4..+3; per row 4 consecutive m = 4 KB contig
        #pragma unroll
        for (int j = 0; j < 4; ++j) {
            const int row = w * 4 + j;
            float* op = out + ((size_t)(rowbase + row) * MSUB + mm * 4) * KC + 4 * lane;
            #pragma unroll
            for (int ms = 0; ms < 4; ++ms) {
                f32x4 v = *(const f32x4*)&stg[row][ms][4 * lane];
                *(f32x4*)(op + ms * KC) = v;
            }
        }
        __syncthreads();
    }
}

extern "C" void kernel_launch(void* const* d_in, const int* in_sizes, int n_in,
                              void* d_out, int out_size, void* d_ws, size_t ws_size,
                              hipStream_t stream) {
    const float* x   = (const float*)d_in[0];   // [32768, 768]
    const float* cbk = (const float*)d_in[1];   // [32, 256, 24]
    const float* rot = (const float*)d_in[2];   // [768, 768]
    float* out = (float*)d_out;                 // [32768, 32, 256]

    char* ws = (char*)d_ws;
    bf16* cb_pad = (bf16*)(ws);
    bf16* rot_bf = (bf16*)(ws + (1u << 20));
    bf16* xrb    = (bf16*)(ws + (4u << 20));

    hipLaunchKernelGGL(pq_prep,    dim3(416),  dim3(256), 0, stream, cbk, rot, cb_pad, rot_bf);
    hipLaunchKernelGGL(pq_rot,     dim3(1024), dim3(512), 0, stream, x, rot_bf, xrb);
    hipLaunchKernelGGL(pq_scores6, dim3(2048), dim3(256), 0, stream, xrb, cb_pad, out);
}

// Round 10
// 434.339 us; speedup vs baseline: 1.7773x; 1.0279x over previous
//
#include <hip/hip_runtime.h>
#include <hip/hip_bf16.h>

typedef __bf16 bf16;
typedef __bf16 bf16x4 __attribute__((ext_vector_type(4)));
typedef __bf16 bf16x8 __attribute__((ext_vector_type(8)));
typedef float f32x4 __attribute__((ext_vector_type(4)));

#define NB   32768
#define EMB  768
#define MSUB 32
#define KC   256
#define DSUB 24

// ws layout (bytes):
//   [0,     512K )  cb_pad: bf16 [32][256][32]  (d padded 24->32 with zeros)
//   [1M,  2.125M)  rot_bf: bf16 [768][768]
//   [4M,    54M )  xrb   : bf16 [32768][768]    (natural layout)

__device__ __forceinline__ bf16x8 cvt8(float4 a, float4 b) {
    bf16x8 r;
    r[0] = (bf16)a.x; r[1] = (bf16)a.y; r[2] = (bf16)a.z; r[3] = (bf16)a.w;
    r[4] = (bf16)b.x; r[5] = (bf16)b.y; r[6] = (bf16)b.z; r[7] = (bf16)b.w;
    return r;
}

// LDS-only barrier: waits LDS ops (lgkmcnt) but NOT global stores (vmcnt),
// so the store queue stays full across phases. Stage/drain ordering is
// purely an LDS hazard; global stores never need mid-kernel draining.
__device__ __forceinline__ void lds_barrier() {
    asm volatile("s_waitcnt lgkmcnt(0)" ::: "memory");
    __builtin_amdgcn_s_barrier();
    __builtin_amdgcn_sched_barrier(0);
}

// ---------------------------------------------------------------- kernel 0
__global__ __launch_bounds__(256, 4)
void pq_prep(const float* __restrict__ cb, const float* __restrict__ rot,
             bf16* __restrict__ cb_pad, bf16* __restrict__ rot_bf) {
    const int b = blockIdx.x;
    const int t = threadIdx.x;
    if (b < 288) {                       // rot: 768*768 = 288*2048
        const int o = b * 2048 + t * 8;
        float4 a0 = *(const float4*)(rot + o);
        float4 a1 = *(const float4*)(rot + o + 4);
        *(bf16x8*)(rot_bf + o) = cvt8(a0, a1);
    } else {                             // cb pad+cvt: [m][k][24] -> bf16 [m][k][32]
        const int o  = (b - 288) * 2048 + t * 8;   // 32*256*32 = 128*2048
        const int m  = o >> 13;
        const int k  = (o >> 5) & 255;
        const int d0 = o & 31;           // 0,8,16,24
        bf16x8 v;
        if (d0 < DSUB) {
            const float* cp = cb + (size_t)(m * KC + k) * DSUB + d0;
            v = cvt8(*(const float4*)cp, *(const float4*)(cp + 4));
        } else {
            const float4 fz = {0.f, 0.f, 0.f, 0.f};
            v = cvt8(fz, fz);
        }
        *(bf16x8*)(cb_pad + o) = v;
    }
}

// ---------------------------------------------------------------- kernel 1
// xr = x @ rot^T via swapped MFMA: D[j][row] = mfma(A=rot_frag, B=x_frag).
// Acc regs hold 4 CONSECUTIVE j per lane -> direct bf16x4 stores.
__global__ __launch_bounds__(512, 3)
void pq_rot(const float* __restrict__ x, const bf16* __restrict__ rot_bf,
            bf16* __restrict__ xrb) {
    __shared__ bf16 g_lds[96 * 32 * 8];   // x bf16 granules [e8][row][slot], 48 KiB

    const int tid  = threadIdx.x;
    const int w    = tid >> 6;
    const int lane = tid & 63;
    const int l15  = lane & 15;
    const int lg   = lane >> 4;
    const int rowbase = blockIdx.x * 32;

    #pragma unroll
    for (int i = 0; i < 6; ++i) {
        const int oct = i * 512 + tid;
        const int row = oct & 31;
        const int e8  = oct >> 5;
        const float* xp = x + (size_t)(rowbase + row) * EMB + e8 * 8;
        *(bf16x8*)&g_lds[(e8 * 32 + row) * 8] =
            cvt8(*(const float4*)xp, *(const float4*)(xp + 4));
    }
    __syncthreads();

    f32x4 acc[2][6];
    #pragma unroll
    for (int rt = 0; rt < 2; ++rt)
        #pragma unroll
        for (int jt = 0; jt < 6; ++jt)
            acc[rt][jt] = (f32x4){0.f, 0.f, 0.f, 0.f};

    const int jbase = w * 96;
    #pragma unroll 2
    for (int e0 = 0; e0 < EMB; e0 += 32) {
        bf16x8 xfrag[2];
        #pragma unroll
        for (int rt = 0; rt < 2; ++rt)
            xfrag[rt] = *(const bf16x8*)&g_lds[(((e0 >> 3) + lg) * 32 + rt * 16 + l15) * 8];
        #pragma unroll
        for (int jt = 0; jt < 6; ++jt) {
            const bf16* bp = rot_bf + (size_t)(jbase + jt * 16 + l15) * EMB + e0 + lg * 8;
            bf16x8 rotfrag = *(const bf16x8*)bp;
            acc[0][jt] = __builtin_amdgcn_mfma_f32_16x16x32_bf16(rotfrag, xfrag[0], acc[0][jt], 0, 0, 0);
            acc[1][jt] = __builtin_amdgcn_mfma_f32_16x16x32_bf16(rotfrag, xfrag[1], acc[1][jt], 0, 0, 0);
        }
    }

    #pragma unroll
    for (int rt = 0; rt < 2; ++rt) {
        #pragma unroll
        for (int jt = 0; jt < 6; ++jt) {
            bf16x4 v;
            #pragma unroll
            for (int r = 0; r < 4; ++r) v[r] = (bf16)acc[rt][jt][r];
            bf16* p = xrb + (size_t)(rowbase + rt * 16 + l15) * EMB
                          + jbase + jt * 16 + lg * 4;
            *(bf16x4*)p = v;
        }
    }
}

// ---------------------------------------------------------------- kernel 2
// scores via MFMA. Block = 4 waves / 16 rows. Phase mm: wave w computes
// m = mm*4+w (16 MFMA), stages C-frags to LDS, raw-barrier (lgkm only),
// then wave w drains rows w*4..w*4+3 as 4 KB contiguous spans. Stores are
// never drained mid-kernel (no vmcnt at barriers) -> store queue stays full.
// Stage row-stride 1044 floats (== 20 mod 32) -> ~2-way stage writes (free);
// drain reads contiguous (conflict-free).
#define STG_ROW 1044
__global__ __launch_bounds__(256, 2)
void pq_scores7(const bf16* __restrict__ xrb, const bf16* __restrict__ cb_pad,
                float* __restrict__ out) {
    __shared__ float stg[16 * STG_ROW];   // 66,816 B -> 2 blocks/CU

    const int tid  = threadIdx.x;
    const int lane = tid & 63;
    const int w    = tid >> 6;          // 0..3
    const int l15  = lane & 15;
    const int hi   = lane >> 4;         // 0..3

    // XCD-bijective swizzle: 2048 blocks, 256 contiguous rowtiles per XCD
    const int bid = (int)blockIdx.x;
    const int swz = (bid & 7) * 256 + (bid >> 3);
    const int rowbase = swz * 16;

    #pragma unroll 1
    for (int mm = 0; mm < 8; ++mm) {
        const int m = mm * 4 + w;

        // xs B-frag: lane -> xrb[rowbase+l15][m*24 + hi*8 ..+7]
        // (hi==3 tail reads d=24..31: finite garbage x cb_pad zeros = 0)
        const bf16* xp = xrb + (size_t)(rowbase + l15) * EMB + m * DSUB + hi * 8;
        bf16x8 xfrag = *(const bf16x8*)xp;

        // 16 k-tiles: A-frag = cb_pad[m][kt*16+l15][hi*8 ..+7]
        const bf16* cbm = cb_pad + (size_t)m * (KC * 32);
        f32x4 acc[16];
        #pragma unroll
        for (int kt = 0; kt < 16; ++kt) {
            bf16x8 cfrag = *(const bf16x8*)(cbm + (kt * 16 + l15) * 32 + hi * 8);
            acc[kt] = __builtin_amdgcn_mfma_f32_16x16x32_bf16(
                cfrag, xfrag, (f32x4){0.f, 0.f, 0.f, 0.f}, 0, 0, 0);
        }

        // stage: lane l, reg r -> D[kc = kt*16+hi*4+r][docrow = l15]
        #pragma unroll
        for (int kt = 0; kt < 16; ++kt)
            *(f32x4*)&stg[l15 * STG_ROW + w * 260 + kt * 16 + hi * 4] = acc[kt];

        lds_barrier();   // stage visible; does NOT drain global stores

        // drain: wave w -> rows w*4..+3; per row 4 consecutive m = 4 KB contig
        #pragma unroll
        for (int j = 0; j < 4; ++j) {
            const int row = w * 4 + j;
            float* op = out + ((size_t)(rowbase + row) * MSUB + mm * 4) * KC + 4 * lane;
            #pragma unroll
            for (int ms = 0; ms < 4; ++ms) {
                f32x4 v = *(const f32x4*)&stg[row * STG_ROW + ms * 260 + 4 * lane];
                *(f32x4*)(op + ms * KC) = v;
            }
        }

        lds_barrier();   // drain reads done before next stage overwrites
    }
}

extern "C" void kernel_launch(void* const* d_in, const int* in_sizes, int n_in,
                              void* d_out, int out_size, void* d_ws, size_t ws_size,
                              hipStream_t stream) {
    const float* x   = (const float*)d_in[0];   // [32768, 768]
    const float* cbk = (const float*)d_in[1];   // [32, 256, 24]
    const float* rot = (const float*)d_in[2];   // [768, 768]
    float* out = (float*)d_out;                 // [32768, 32, 256]

    char* ws = (char*)d_ws;
    bf16* cb_pad = (bf16*)(ws);
    bf16* rot_bf = (bf16*)(ws + (1u << 20));
    bf16* xrb    = (bf16*)(ws + (4u << 20));

    hipLaunchKernelGGL(pq_prep,     dim3(416),  dim3(256), 0, stream, cbk, rot, cb_pad, rot_bf);
    hipLaunchKernelGGL(pq_rot,      dim3(1024), dim3(512), 0, stream, x, rot_bf, xrb);
    hipLaunchKernelGGL(pq_scores7,  dim3(2048), dim3(256), 0, stream, xrb, cb_pad, out);
}